// Round 1
// baseline (526.218 us; speedup 1.0000x reference)
//
#include <hip/hip_runtime.h>
#include <stdint.h>

// Problem: B=8, Lq=Lv=2048, Din=Dout=512, all f32 in/out.
// out[b][l][0:512)=o, [512:1024)=q, [1024:1536)=mv broadcast.
// ws usage (~51.3 MB): qw bf16 | v bf16 | vT bf16 | kT bf16 | mv f32 | mv partial

typedef __attribute__((ext_vector_type(8))) short short8v;
typedef __attribute__((ext_vector_type(4))) float f32x4;

#define LQ 2048
#define LV 2048
#define DIN 512
#define DOUT 512
#define NB 8

__device__ __forceinline__ unsigned short f2bf(float x){
    union { float f; unsigned u; } v; v.f = x;
    unsigned r = v.u + 0x7fffu + ((v.u >> 16) & 1u);
    return (unsigned short)(r >> 16);
}

// kernel [DIN][DOUT] f32 -> kT [DOUT][DIN] bf16, scaled by 0.1 (folds the /10)
__global__ void prep_kT(const float* __restrict__ k, unsigned short* __restrict__ kT){
    __shared__ float tile[32][33];
    int tx = threadIdx.x & 31, ty = threadIdx.x >> 5;
    int kb = blockIdx.x, eb = blockIdx.y;
    #pragma unroll
    for (int p = 0; p < 4; ++p){
        int r = ty + p*8;
        tile[r][tx] = k[(size_t)(kb*32 + r)*DOUT + eb*32 + tx];
    }
    __syncthreads();
    #pragma unroll
    for (int p = 0; p < 4; ++p){
        int r = ty + p*8;
        kT[(size_t)(eb*32 + r)*DIN + kb*32 + tx] = f2bf(tile[tx][r] * 0.1f);
    }
}

// v f32 -> v bf16 (natural [b][j][e]) and vT bf16 ([b][e][j])
__global__ void prep_v(const float* __restrict__ v, unsigned short* __restrict__ vbf,
                       unsigned short* __restrict__ vT){
    __shared__ float tile[32][33];
    int tx = threadIdx.x & 31, ty = threadIdx.x >> 5;
    int jb = blockIdx.x, eb = blockIdx.y, b = blockIdx.z;
    const size_t vbase = (size_t)b*LV*DOUT;
    #pragma unroll
    for (int p = 0; p < 4; ++p){
        int r = ty + p*8;
        size_t idx = vbase + (size_t)(jb*32 + r)*DOUT + eb*32 + tx;
        float val = v[idx];
        tile[r][tx] = val;
        vbf[idx] = f2bf(val);
    }
    __syncthreads();
    const size_t tbase = (size_t)b*DOUT*LV;
    #pragma unroll
    for (int p = 0; p < 4; ++p){
        int r = ty + p*8;
        vT[tbase + (size_t)(eb*32 + r)*LV + jb*32 + tx] = f2bf(tile[tx][r]);
    }
}

// masked max over the value sequence, two-stage
__global__ void mv_partial(const float* __restrict__ v, const float* __restrict__ mask,
                           float* __restrict__ part){
    int b = blockIdx.x, ch = blockIdx.y;
    int e = threadIdx.x; // 512
    float m = -3e38f;
    for (int j = ch*128; j < ch*128 + 128; ++j){
        float msk = mask[b*LV + j];
        float val = v[((size_t)b*LV + j)*DOUT + e];
        m = fmaxf(m, val - (1.0f - msk)*1e10f);
    }
    part[((size_t)b*16 + ch)*DOUT + e] = m;
}

__global__ void mv_final(const float* __restrict__ part, float* __restrict__ mv){
    int b = blockIdx.x; int e = threadIdx.x;
    float m = -3e38f;
    #pragma unroll
    for (int c = 0; c < 16; ++c) m = fmaxf(m, part[((size_t)b*16 + c)*DOUT + e]);
    mv[b*DOUT + e] = m;
}

// qw[b*Lq+l][e] = sum_d q[..][d] * kT[e][d]  (bf16 MFMA, f32 acc, bf16 out)
__global__ __launch_bounds__(256) void gemm_qw(const float* __restrict__ q,
                                               const unsigned short* __restrict__ kT,
                                               unsigned short* __restrict__ qw){
    int bid = blockIdx.x;
    int mb = bid >> 1, nb = bid & 1;
    int w = threadIdx.x >> 6, lane = threadIdx.x & 63;
    int li = lane & 15, lg = lane >> 4;
    int i0 = mb*64 + w*16;
    int n0 = nb*256;
    f32x4 acc[16];
    #pragma unroll
    for (int t = 0; t < 16; ++t) acc[t] = (f32x4){0.f,0.f,0.f,0.f};
    for (int ks = 0; ks < 16; ++ks){
        const float* qp = q + (size_t)(i0 + li)*DIN + ks*32 + lg*8;
        float4 lo = *(const float4*)qp;
        float4 hi = *(const float4*)(qp + 4);
        short8v af;
        af[0]=(short)f2bf(lo.x); af[1]=(short)f2bf(lo.y); af[2]=(short)f2bf(lo.z); af[3]=(short)f2bf(lo.w);
        af[4]=(short)f2bf(hi.x); af[5]=(short)f2bf(hi.y); af[6]=(short)f2bf(hi.z); af[7]=(short)f2bf(hi.w);
        #pragma unroll
        for (int t = 0; t < 16; ++t){
            short8v bf = *(const short8v*)(kT + (size_t)(n0 + t*16 + li)*DIN + ks*32 + lg*8);
            acc[t] = __builtin_amdgcn_mfma_f32_16x16x32_bf16(af, bf, acc[t], 0, 0, 0);
        }
    }
    #pragma unroll
    for (int t = 0; t < 16; ++t)
        #pragma unroll
        for (int r = 0; r < 4; ++r)
            qw[(size_t)(i0 + 4*lg + r)*DOUT + n0 + t*16 + li] = f2bf(acc[t][r]);
}

// Flash attention: 4 waves x 16 q-rows, KV tile 32.
// S^T = mfma(A=v, B=qw) so each lane owns one q-row's softmax state.
__global__ __launch_bounds__(256, 1) void flash(const unsigned short* __restrict__ qw,
                                                const unsigned short* __restrict__ vbf,
                                                const unsigned short* __restrict__ vT,
                                                const float* __restrict__ mask,
                                                float* __restrict__ out){
    __shared__ short vT_lds[512][40];   // padded: 80B row stride -> 2-way bank alias only
    __shared__ short P_lds[4][16][40];
    __shared__ float bias_lds[32];

    int bid = blockIdx.x;
    int b = bid & 7;               // batch -> XCD (bid%8) for v L2 locality
    int m0 = (bid >> 3) * 64;
    int tid = threadIdx.x;
    int w = tid >> 6, lane = tid & 63;
    int li = lane & 15, lg = lane >> 4;
    int i0 = m0 + w*16;

    // q B-fragments: B[k=d][n=i]; lane holds qw[i0+li][ks*32+lg*8 ..+7]
    short8v qf[16];
    const unsigned short* qrow = qw + (size_t)(b*LQ + i0 + li)*DIN;
    #pragma unroll
    for (int ks = 0; ks < 16; ++ks)
        qf[ks] = *(const short8v*)(qrow + ks*32 + lg*8);

    f32x4 accO[32];
    #pragma unroll
    for (int t = 0; t < 32; ++t) accO[t] = (f32x4){0.f,0.f,0.f,0.f};
    float mrun = -1e30f, srun = 0.0f;

    const unsigned short* vb  = vbf + (size_t)b*LV*DOUT;
    const unsigned short* vTb = vT  + (size_t)b*DOUT*LV;

    for (int jt = 0; jt < 64; ++jt){
        int j0 = jt*32;
        __syncthreads();   // protect previous tile's LDS reads
        {   // stage vT tile [512 e][32 j] + mask bias
            int rr = tid >> 2, cc = (tid & 3)*8;
            #pragma unroll
            for (int p = 0; p < 8; ++p){
                int e = p*64 + rr;
                *(short8v*)&vT_lds[e][cc] = *(const short8v*)(vTb + (size_t)e*LV + j0 + cc);
            }
            if (tid < 32) bias_lds[tid] = (mask[b*LV + j0 + tid] - 1.0f)*1e10f;
        }
        __syncthreads();

        // S^T tiles: D[m=j][n=i]; lane: rows j = s*16 + 4*lg + r, col i = i0+li
        f32x4 st0 = (f32x4){0.f,0.f,0.f,0.f}, st1 = (f32x4){0.f,0.f,0.f,0.f};
        #pragma unroll
        for (int ks = 0; ks < 16; ++ks){
            short8v a0 = *(const short8v*)(vb + (size_t)(j0 + li)*DOUT + ks*32 + lg*8);
            st0 = __builtin_amdgcn_mfma_f32_16x16x32_bf16(a0, qf[ks], st0, 0, 0, 0);
        }
        #pragma unroll
        for (int ks = 0; ks < 16; ++ks){
            short8v a1 = *(const short8v*)(vb + (size_t)(j0 + 16 + li)*DOUT + ks*32 + lg*8);
            st1 = __builtin_amdgcn_mfma_f32_16x16x32_bf16(a1, qf[ks], st1, 0, 0, 0);
        }

        float sv[8];
        #pragma unroll
        for (int r = 0; r < 4; ++r){
            sv[r]     = st0[r] + bias_lds[4*lg + r];
            sv[4 + r] = st1[r] + bias_lds[16 + 4*lg + r];
        }
        float pmax = sv[0];
        #pragma unroll
        for (int k = 1; k < 8; ++k) pmax = fmaxf(pmax, sv[k]);
        pmax = fmaxf(pmax, __shfl_xor(pmax, 16));
        pmax = fmaxf(pmax, __shfl_xor(pmax, 32));
        float mnew = fmaxf(mrun, pmax);
        float al = __expf(mrun - mnew);
        float p[8]; float psum = 0.f;
        #pragma unroll
        for (int k = 0; k < 8; ++k){ p[k] = __expf(sv[k] - mnew); psum += p[k]; }
        psum += __shfl_xor(psum, 16);
        psum += __shfl_xor(psum, 32);
        srun = srun*al + psum;
        mrun = mnew;

        if (!__all(al == 1.0f)){  // skip O-rescale when running max unchanged (common)
            float alr[4];
            #pragma unroll
            for (int r = 0; r < 4; ++r) alr[r] = __shfl(al, 4*lg + r);
            #pragma unroll
            for (int t = 0; t < 32; ++t)
                #pragma unroll
                for (int r = 0; r < 4; ++r) accO[t][r] *= alr[r];
        }

        // pack P -> LDS [i=li][j], then read PV A-fragment A[i=li][j=8*lg..+7]
        #pragma unroll
        for (int s2 = 0; s2 < 2; ++s2)
            #pragma unroll
            for (int k = 0; k < 2; ++k){
                unsigned lo2 = f2bf(p[s2*4 + 2*k]);
                unsigned hi2 = f2bf(p[s2*4 + 2*k + 1]);
                *(unsigned*)&P_lds[w][li][s2*16 + 4*lg + 2*k] = lo2 | (hi2 << 16);
            }
        short8v pa = *(const short8v*)&P_lds[w][li][lg*8];   // same-wave RAW: compiler waits lgkmcnt

        #pragma unroll
        for (int t = 0; t < 32; ++t){
            short8v vf = *(const short8v*)&vT_lds[t*16 + li][lg*8]; // B[k=j][n=e]
            accO[t] = __builtin_amdgcn_mfma_f32_16x16x32_bf16(pa, vf, accO[t], 0, 0, 0);
        }
    }

    // epilogue: O /= s ; acc rows are i0 + 4*lg + r, their s lives in lanes 0..15
    float inv[4];
    #pragma unroll
    for (int r = 0; r < 4; ++r){ float sr = __shfl(srun, 4*lg + r); inv[r] = 1.0f / sr; }
    #pragma unroll
    for (int t = 0; t < 32; ++t)
        #pragma unroll
        for (int r = 0; r < 4; ++r)
            out[(size_t)(b*LQ + i0 + 4*lg + r)*1536 + t*16 + li] = accO[t][r]*inv[r];
}

// q passthrough + mv broadcast into out sections 1 and 2 (exact f32)
__global__ void copy_qmv(const float* __restrict__ q, const float* __restrict__ mv,
                         float* __restrict__ out){
    const float4* q4  = (const float4*)q;
    const float4* mv4 = (const float4*)mv;
    float4* o4 = (float4*)out;
    int total = NB*LQ*256;  // 256 float4 per row (128 q + 128 mv)
    for (int idx = blockIdx.x*blockDim.x + threadIdx.x; idx < total; idx += gridDim.x*blockDim.x){
        int c = idx & 255;
        int row = idx >> 8;       // b*LQ + l
        int b = row >> 11;
        if (c < 128) o4[(size_t)row*384 + 128 + c] = q4[(size_t)row*128 + c];
        else         o4[(size_t)row*384 + 128 + c] = mv4[b*128 + (c - 128)];
    }
}

extern "C" void kernel_launch(void* const* d_in, const int* in_sizes, int n_in,
                              void* d_out, int out_size, void* d_ws, size_t ws_size,
                              hipStream_t stream){
    const float* q     = (const float*)d_in[0];
    const float* v     = (const float*)d_in[1];
    const float* vmask = (const float*)d_in[2];
    const float* kern  = (const float*)d_in[3];
    float* out = (float*)d_out;
    char* ws = (char*)d_ws;

    const size_t SZ_QW = (size_t)NB*LQ*DOUT*2;   // 16 MB
    unsigned short* qw  = (unsigned short*)(ws);
    unsigned short* vbf = (unsigned short*)(ws + SZ_QW);
    unsigned short* vT  = (unsigned short*)(ws + 2*SZ_QW);
    unsigned short* kT  = (unsigned short*)(ws + 3*SZ_QW);
    float* mv   = (float*)(ws + 3*SZ_QW + 524288);
    float* part = (float*)(ws + 3*SZ_QW + 524288 + 16384);

    hipLaunchKernelGGL(prep_kT,   dim3(16,16),   dim3(256), 0, stream, kern, kT);
    hipLaunchKernelGGL(prep_v,    dim3(64,16,8), dim3(256), 0, stream, v, vbf, vT);
    hipLaunchKernelGGL(mv_partial,dim3(8,16),    dim3(512), 0, stream, v, vmask, part);
    hipLaunchKernelGGL(mv_final,  dim3(8),       dim3(512), 0, stream, part, mv);
    hipLaunchKernelGGL(gemm_qw,   dim3(512),     dim3(256), 0, stream, q, kT, qw);
    hipLaunchKernelGGL(flash,     dim3(256),     dim3(256), 0, stream, qw, vbf, vT, vmask, out);
    hipLaunchKernelGGL(copy_qmv,  dim3(2048),    dim3(256), 0, stream, q, mv, out);
}